// Round 11
// baseline (229.121 us; speedup 1.0000x reference)
//
#include <hip/hip_runtime.h>

typedef __attribute__((ext_vector_type(8))) short short8v;
typedef __attribute__((ext_vector_type(4))) short short4v;
typedef __attribute__((ext_vector_type(4))) float float4v;

// fp32 -> bf16 via native cast: compiler emits v_cvt_pk_bf16_f32 (RNE).
__device__ __forceinline__ short f2bf(float f) {
  __bf16 h = (__bf16)f;
  return __builtin_bit_cast(short, h);
}

__device__ __forceinline__ short8v cvt8(float4 a, float4 b) {
  short8v r;
  r[0] = f2bf(a.x); r[1] = f2bf(a.y); r[2] = f2bf(a.z); r[3] = f2bf(a.w);
  r[4] = f2bf(b.x); r[5] = f2bf(b.y); r[6] = f2bf(b.z); r[7] = f2bf(b.w);
  return r;
}

// Load 8 contiguous f32 from global and convert to a bf16x8 MFMA fragment.
// Used for weight fragments: B/A are 16 KB each -> L1/L2-resident after the
// first block generation on a CU; no LDS staging needed.
__device__ __forceinline__ short8v load_frag8(const float* __restrict__ p) {
  float4 a = reinterpret_cast<const float4*>(p)[0];
  float4 b = reinterpret_cast<const float4*>(p)[1];
  return cvt8(a, b);
}

// R10 post-mortem: 55.5us, all pipes idle, occupancy 37% capped by 32 KB
// LDS (half of it weight staging) and launch_bounds(256,4). This version
// drops weight LDS staging entirely (fragments loaded straight from global,
// L1/L2-hit), freeing 16 KB -> LDS = y1 only (16 KB/block), deleting the
// weight-staging chain + one barrier from the block critical path, and
// raising residency to 5 blocks/CU = 20 waves/CU via launch_bounds(256,5)
// (VGPR cap 102, est. liveness ~90).
// Block (4 waves) = 2 rows; wave (w>>1 = row slot, w&1 = half) hoists all
// 8 of its x dwordx4 up-front, computes stage-1 for its a-half into the
// row-shared y1 (XOR-swizzled), ONE __syncthreads, then stage-2 q-half.
__global__ __launch_bounds__(256, 5)
void kron64_kernel(const float* __restrict__ x, const float* __restrict__ A,
                   const float* __restrict__ B, const float* __restrict__ bias,
                   float* __restrict__ out) {
  __shared__ short y1[2][4096];  // per-ROW Y1^T (64q x 64a bf16), 16 KB

  const int tid = threadIdx.x;
  const int w = tid >> 6;
  const int lane = tid & 63;
  const int g = lane >> 4;       // lane group 0..3
  const int c = lane & 15;       // lane-in-group 0..15
  const int swz = (c & 7) << 3;  // element-index XOR swizzle (row&7 == c&7)

  const int rs = w >> 1;         // row slot in block (0,1)
  const int half = w & 1;        // a-half (stage 1) / q-half (stage 2)
  const int m = blockIdx.x * 2 + rs;
  const float* xm = x + (size_t)m * 4096;
  short* yw = y1[rs];
  const float4v vzero = {0.f, 0.f, 0.f, 0.f};

  // ---- hoist ALL x loads for this wave's a-half: 8 dwordx4, 32 VGPR ----
  const int A0 = 2 * half;  // at in {A0, A0+1}
  float4 xb[8];
  {
    const float* base = xm + (16 * A0 + c) * 64 + 8 * g;
#pragma unroll
    for (int atl = 0; atl < 2; ++atl)
#pragma unroll
      for (int kk = 0; kk < 2; ++kk) {
        const float* p = base + atl * 1024 + kk * 32;
        xb[(atl * 2 + kk) * 2 + 0] = reinterpret_cast<const float4*>(p)[0];
        xb[(atl * 2 + kk) * 2 + 1] = reinterpret_cast<const float4*>(p)[1];
      }
  }

  // ---------------- Stage 1: C1[a-half] = Xm_half * B^T ----------------
  // B fragment (qt,kk): B[16qt+c][32kk+8g .. +7], loaded direct from global
  // (L1/L2-hit; compiler hoists/schedules these ahead of the MFMA chain).
#pragma unroll
  for (int atl = 0; atl < 2; ++atl) {
    const int at = A0 + atl;
    float4v acc[4];
#pragma unroll
    for (int qt = 0; qt < 4; ++qt) acc[qt] = vzero;
#pragma unroll
    for (int kk = 0; kk < 2; ++kk) {
      short8v xf = cvt8(xb[(atl * 2 + kk) * 2], xb[(atl * 2 + kk) * 2 + 1]);
#pragma unroll
      for (int qt = 0; qt < 4; ++qt) {
        short8v bfrk = load_frag8(B + (16 * qt + c) * 64 + 32 * kk + 8 * g);
        acc[qt] = __builtin_amdgcn_mfma_f32_16x16x32_bf16(
            xf, bfrk, acc[qt], 0, 0, 0);
      }
    }
    // lane holds C1[16at+4g+b][16qt+c]; store transposed Y1T[q][a], swizzled
#pragma unroll
    for (int qt = 0; qt < 4; ++qt) {
      short4v v;
      v[0] = f2bf(acc[qt][0]); v[1] = f2bf(acc[qt][1]);
      v[2] = f2bf(acc[qt][2]); v[3] = f2bf(acc[qt][3]);
      int idx = ((16 * qt + c) * 64 + 16 * at + 4 * g) ^ swz;
      *reinterpret_cast<short4v*>(&yw[idx]) = v;
    }
  }

  __syncthreads();  // both a-halves of each row's y1 complete (only barrier)

  // ---------------- Stage 2: C2^T[q-half] = Y1^T * A^T ----------------
  {
    short8v yfr[2][2];  // frag(qtl,kk): Y1T[16(2*half+qtl)+c][32kk+8g+i]
#pragma unroll
    for (int qtl = 0; qtl < 2; ++qtl)
#pragma unroll
      for (int kk = 0; kk < 2; ++kk) {
        int idx = ((16 * (2 * half + qtl) + c) * 64) + ((32 * kk + 8 * g) ^ swz);
        yfr[qtl][kk] = *reinterpret_cast<const short8v*>(&yw[idx]);
      }

    float* om = out + (size_t)m * 4096;
#pragma unroll
    for (int pt = 0; pt < 4; ++pt) {
      short8v afr[2];  // frag(kk): A[16pt+c][32kk+8g+i], direct from global
#pragma unroll
      for (int kk = 0; kk < 2; ++kk)
        afr[kk] = load_frag8(A + (16 * pt + c) * 64 + 32 * kk + 8 * g);
#pragma unroll
      for (int qtl = 0; qtl < 2; ++qtl) {
        // lane holds C2[p=16pt+c][q=16(2*half+qtl)+4g+b] -> n = p*64+q
        const int n = (16 * pt + c) * 64 + 16 * (2 * half + qtl) + 4 * g;
        float4 bv = *reinterpret_cast<const float4*>(bias + n);
        float4v acc; acc[0] = bv.x; acc[1] = bv.y; acc[2] = bv.z; acc[3] = bv.w;
#pragma unroll
        for (int kk = 0; kk < 2; ++kk)
          acc = __builtin_amdgcn_mfma_f32_16x16x32_bf16(
              yfr[qtl][kk], afr[kk], acc, 0, 0, 0);
        *reinterpret_cast<float4v*>(om + n) = acc;
      }
    }
  }
}

extern "C" void kernel_launch(void* const* d_in, const int* in_sizes, int n_in,
                              void* d_out, int out_size, void* d_ws, size_t ws_size,
                              hipStream_t stream) {
  (void)in_sizes; (void)n_in; (void)out_size; (void)d_ws; (void)ws_size;
  const float* x    = (const float*)d_in[0];
  const float* A    = (const float*)d_in[1];
  const float* B    = (const float*)d_in[2];
  const float* bias = (const float*)d_in[3];
  float* out = (float*)d_out;

  dim3 grid(4096), block(256);
  hipLaunchKernelGGL(kron64_kernel, grid, block, 0, stream, x, A, B, bias, out);
}

// Round 12
// 55.479 us; speedup vs baseline: 4.1299x; 4.1299x over previous
//
#include <hip/hip_runtime.h>

typedef __attribute__((ext_vector_type(8))) short short8v;
typedef __attribute__((ext_vector_type(4))) short short4v;
typedef __attribute__((ext_vector_type(4))) float float4v;

// fp32 -> bf16 via native cast: compiler emits v_cvt_pk_bf16_f32 (RNE).
__device__ __forceinline__ short f2bf(float f) {
  __bf16 h = (__bf16)f;
  return __builtin_bit_cast(short, h);
}

__device__ __forceinline__ short8v cvt8(float4 a, float4 b) {
  short8v r;
  r[0] = f2bf(a.x); r[1] = f2bf(a.y); r[2] = f2bf(a.z); r[3] = f2bf(a.w);
  r[4] = f2bf(b.x); r[5] = f2bf(b.y); r[6] = f2bf(b.z); r[7] = f2bf(b.w);
  return r;
}

// Stage a 64x64 f32 matrix into LDS as bf16, XOR-swizzled:
// element (r, col) -> dst[r*64 + (col ^ ((r&7)<<3))].
__device__ __forceinline__ void stage_weight(const float* __restrict__ src,
                                             short* __restrict__ dst, int tid) {
  const int r = tid >> 2;
  const int c0 = (tid & 3) << 4;
  const float* p = src + r * 64 + c0;
  float4 f0 = reinterpret_cast<const float4*>(p)[0];
  float4 f1 = reinterpret_cast<const float4*>(p)[1];
  float4 f2 = reinterpret_cast<const float4*>(p)[2];
  float4 f3 = reinterpret_cast<const float4*>(p)[3];
  short8v g0 = cvt8(f0, f1), g1 = cvt8(f2, f3);
  const int sw = (r & 7) << 3;
  *reinterpret_cast<short8v*>(&dst[r * 64 + ((c0)     ^ sw)]) = g0;
  *reinterpret_cast<short8v*>(&dst[r * 64 + ((c0 + 8) ^ sw)]) = g1;
}

constexpr int GENS = 4;  // row-pairs per block; grid = 8192/(2*GENS) = 1024

// R11 post-mortem: dropping weight LDS staging spilled (~380 MB scratch
// traffic). This round keeps R10's winning shape (lean half-row waves,
// LDS weights, 32 KB/block) and attacks block-lifecycle serialization:
// (1) generation loop: block stages weights once, processes 4 row-pairs;
// (2) NON-DRAINING barriers: lgkmcnt(0)-only fence + raw s_barrier — y1
//     ordering needs only the DS counter; __syncthreads would emit
//     s_waitcnt vmcnt(0) and drain prefetch loads + output stores;
// (3) cross-gen x prefetch into a second 32-VGPR buffer, issued right
//     after stage-1 consumes the current one -> in flight across barrier,
//     stage-2, and the gen-end barrier.
// Liveness est ~108: (256,2) historically lands 116-128 w/o spill.
__global__ __launch_bounds__(256, 2)
void kron64_kernel(const float* __restrict__ x, const float* __restrict__ A,
                   const float* __restrict__ B, const float* __restrict__ bias,
                   float* __restrict__ out) {
  __shared__ short bw[4096];     // B bf16 [64][64] swizzled, 8 KB
  __shared__ short aw[4096];     // A bf16 [64][64] swizzled, 8 KB
  __shared__ short y1[2][4096];  // per-ROW Y1^T (64q x 64a bf16), 16 KB

  const int tid = threadIdx.x;
  const int w = tid >> 6;
  const int lane = tid & 63;
  const int g = lane >> 4;       // lane group 0..3
  const int c = lane & 15;       // lane-in-group 0..15
  const int swz = (c & 7) << 3;  // element-index XOR swizzle (row&7 == c&7)

  const int rs = w >> 1;         // row slot in block (0,1)
  const int half = w & 1;        // a-half (stage 1) / q-half (stage 2)
  const int A0 = 2 * half;       // stage-1 at in {A0, A0+1}
  const int mbase = blockIdx.x * (2 * GENS);
  short* yw = y1[rs];
  const float4v vzero = {0.f, 0.f, 0.f, 0.f};

  stage_weight(B, bw, tid);
  stage_weight(A, aw, tid);

  float4 xb0[8], xb1[8];  // double-buffered half-row x, 32 VGPR each

  auto issue = [&](float4* buf, int m) {
    const float* base = x + (size_t)m * 4096 + (16 * A0 + c) * 64 + 8 * g;
#pragma unroll
    for (int atl = 0; atl < 2; ++atl)
#pragma unroll
      for (int kk = 0; kk < 2; ++kk) {
        const float* p = base + atl * 1024 + kk * 32;
        buf[(atl * 2 + kk) * 2 + 0] = reinterpret_cast<const float4*>(p)[0];
        buf[(atl * 2 + kk) * 2 + 1] = reinterpret_cast<const float4*>(p)[1];
      }
  };

  // lgkmcnt-only barrier: orders LDS traffic across waves WITHOUT draining
  // vmcnt (prefetch loads / output stores stay in flight). The trailing
  // empty asm pins post-barrier memory ops below the barrier.
  auto lgkm_barrier = [&]() {
    __asm__ volatile("s_waitcnt lgkmcnt(0)" ::: "memory");
    __builtin_amdgcn_s_barrier();
    __asm__ volatile("" ::: "memory");
  };

  issue(xb0, mbase + rs);  // gen-0 loads, in flight through the barrier
  lgkm_barrier();          // weights staged

#pragma unroll
  for (int gen = 0; gen < GENS; ++gen) {
    const int m = mbase + 2 * gen + rs;
    float4* cur = (gen & 1) ? xb1 : xb0;
    float4* nxt = (gen & 1) ? xb0 : xb1;

    // ---------------- Stage 1: C1[a-half] = Xm_half * B^T ----------------
#pragma unroll
    for (int atl = 0; atl < 2; ++atl) {
      const int at = A0 + atl;
      float4v acc[4];
#pragma unroll
      for (int qt = 0; qt < 4; ++qt) acc[qt] = vzero;
#pragma unroll
      for (int kk = 0; kk < 2; ++kk) {
        short8v xf = cvt8(cur[(atl * 2 + kk) * 2], cur[(atl * 2 + kk) * 2 + 1]);
#pragma unroll
        for (int qt = 0; qt < 4; ++qt) {
          short8v bfrk = *reinterpret_cast<const short8v*>(
              &bw[(16 * qt + c) * 64 + ((32 * kk + 8 * g) ^ swz)]);
          acc[qt] = __builtin_amdgcn_mfma_f32_16x16x32_bf16(
              xf, bfrk, acc[qt], 0, 0, 0);
        }
      }
      // lane holds C1[16at+4g+b][16qt+c]; store transposed Y1T[q][a], swizzled
#pragma unroll
      for (int qt = 0; qt < 4; ++qt) {
        short4v v;
        v[0] = f2bf(acc[qt][0]); v[1] = f2bf(acc[qt][1]);
        v[2] = f2bf(acc[qt][2]); v[3] = f2bf(acc[qt][3]);
        int idx = ((16 * qt + c) * 64 + 16 * at + 4 * g) ^ swz;
        *reinterpret_cast<short4v*>(&yw[idx]) = v;
      }
    }

    // cur consumed -> prefetch next generation's half-row (stays in flight
    // across both barriers and all of stage 2).
    if (gen + 1 < GENS) issue(nxt, m + 2);

    lgkm_barrier();  // both a-halves of y1 complete

    // ---------------- Stage 2: C2^T[q-half] = Y1^T * A^T ----------------
    {
      short8v yfr[2][2];  // frag(qtl,kk): Y1T[16(2*half+qtl)+c][32kk+8g+i]
#pragma unroll
      for (int qtl = 0; qtl < 2; ++qtl)
#pragma unroll
        for (int kk = 0; kk < 2; ++kk) {
          int idx = ((16 * (2 * half + qtl) + c) * 64) + ((32 * kk + 8 * g) ^ swz);
          yfr[qtl][kk] = *reinterpret_cast<const short8v*>(&yw[idx]);
        }

      float* om = out + (size_t)m * 4096;
#pragma unroll
      for (int pt = 0; pt < 4; ++pt) {
        short8v afr[2];  // frag(kk): A[16pt+c][32kk+8g+i]
#pragma unroll
        for (int kk = 0; kk < 2; ++kk)
          afr[kk] = *reinterpret_cast<const short8v*>(
              &aw[(16 * pt + c) * 64 + ((32 * kk + 8 * g) ^ swz)]);
#pragma unroll
        for (int qtl = 0; qtl < 2; ++qtl) {
          // lane holds C2[p=16pt+c][q=16(2*half+qtl)+4g+b] -> n = p*64+q
          const int n = (16 * pt + c) * 64 + 16 * (2 * half + qtl) + 4 * g;
          float4 bv = *reinterpret_cast<const float4*>(bias + n);
          float4v acc; acc[0] = bv.x; acc[1] = bv.y; acc[2] = bv.z; acc[3] = bv.w;
#pragma unroll
          for (int kk = 0; kk < 2; ++kk)
            acc = __builtin_amdgcn_mfma_f32_16x16x32_bf16(
                yfr[qtl][kk], afr[kk], acc, 0, 0, 0);
          *reinterpret_cast<float4v*>(om + n) = acc;
        }
      }
    }

    // y1 WAR: all stage-2 reads done before next gen's stage-1 writes.
    if (gen + 1 < GENS) lgkm_barrier();
  }
}

extern "C" void kernel_launch(void* const* d_in, const int* in_sizes, int n_in,
                              void* d_out, int out_size, void* d_ws, size_t ws_size,
                              hipStream_t stream) {
  (void)in_sizes; (void)n_in; (void)out_size; (void)d_ws; (void)ws_size;
  const float* x    = (const float*)d_in[0];
  const float* A    = (const float*)d_in[1];
  const float* B    = (const float*)d_in[2];
  const float* bias = (const float*)d_in[3];
  float* out = (float*)d_out;

  dim3 grid(8192 / (2 * GENS)), block(256);
  hipLaunchKernelGGL(kron64_kernel, grid, block, 0, stream, x, A, B, bias, out);
}

// Round 13
// 47.480 us; speedup vs baseline: 4.8256x; 1.1685x over previous
//
#include <hip/hip_runtime.h>

typedef __attribute__((ext_vector_type(8))) short short8v;
typedef __attribute__((ext_vector_type(4))) short short4v;
typedef __attribute__((ext_vector_type(4))) float float4v;

// fp32 -> bf16 via native cast: compiler emits v_cvt_pk_bf16_f32 (RNE).
__device__ __forceinline__ short f2bf(float f) {
  __bf16 h = (__bf16)f;
  return __builtin_bit_cast(short, h);
}

__device__ __forceinline__ short8v cvt8(float4 a, float4 b) {
  short8v r;
  r[0] = f2bf(a.x); r[1] = f2bf(a.y); r[2] = f2bf(a.z); r[3] = f2bf(a.w);
  r[4] = f2bf(b.x); r[5] = f2bf(b.y); r[6] = f2bf(b.z); r[7] = f2bf(b.w);
  return r;
}

// Stage a 64x64 f32 matrix into LDS as bf16, XOR-swizzled:
// element (r, col) -> dst[r*64 + (col ^ ((r&7)<<3))].
__device__ __forceinline__ void stage_weight(const float* __restrict__ src,
                                             short* __restrict__ dst, int tid) {
  const int r = tid >> 2;
  const int c0 = (tid & 3) << 4;
  const float* p = src + r * 64 + c0;
  float4 f0 = reinterpret_cast<const float4*>(p)[0];
  float4 f1 = reinterpret_cast<const float4*>(p)[1];
  float4 f2 = reinterpret_cast<const float4*>(p)[2];
  float4 f3 = reinterpret_cast<const float4*>(p)[3];
  short8v g0 = cvt8(f0, f1), g1 = cvt8(f2, f3);
  const int sw = (r & 7) << 3;
  *reinterpret_cast<short8v*>(&dst[r * 64 + ((c0)     ^ sw)]) = g0;
  *reinterpret_cast<short8v*>(&dst[r * 64 + ((c0 + 8) ^ sw)]) = g1;
}

constexpr int GENS = 4;  // row-pairs per block; grid = 8192/(2*GENS) = 1024

// R12 post-mortem: lifecycle/prefetch fixes all clean but neutral (55.5us,
// FETCH 66 + WRITE 131 MB = 3.6 TB/s). Remaining theory: the write stream
// evicts half of x from L3 every pass (FETCH == x/2 exactly). This round:
// stage-2 results bounce through the DEAD y1 buffer (yfr already in regs)
// re-laid-out so output stores are FULLY CONTIGUOUS (1 KB/instruction =
// 4 complete 256B lines) and NON-TEMPORAL -> writes bypass L3, x stays
// resident. (R3's nt failure was scattered 64B chunks - partial-line
// flushes; full lines remove that mechanism.)
__global__ __launch_bounds__(256, 2)
void kron64_kernel(const float* __restrict__ x, const float* __restrict__ A,
                   const float* __restrict__ B, const float* __restrict__ bias,
                   float* __restrict__ out) {
  __shared__ alignas(16) short bw[4096];     // B bf16 swizzled, 8 KB
  __shared__ alignas(16) short aw[4096];     // A bf16 swizzled, 8 KB
  __shared__ alignas(16) short y1[2][4096];  // per-ROW Y1^T / fp32 outbuf, 16 KB

  const int tid = threadIdx.x;
  const int w = tid >> 6;
  const int lane = tid & 63;
  const int g = lane >> 4;       // lane group 0..3
  const int c = lane & 15;       // lane-in-group 0..15
  const int swz = (c & 7) << 3;  // element-index XOR swizzle (row&7 == c&7)

  const int rs = w >> 1;         // row slot in block (0,1)
  const int half = w & 1;        // a-half (stage 1) / q-half (stage 2)
  const int A0 = 2 * half;       // stage-1 at in {A0, A0+1}
  const int mbase = blockIdx.x * (2 * GENS);
  short* yw = y1[rs];
  const float4v vzero = {0.f, 0.f, 0.f, 0.f};

  stage_weight(B, bw, tid);
  stage_weight(A, aw, tid);

  float4 xb0[8], xb1[8];  // double-buffered half-row x, 32 VGPR each

  auto issue = [&](float4* buf, int m) {
    const float* base = x + (size_t)m * 4096 + (16 * A0 + c) * 64 + 8 * g;
#pragma unroll
    for (int atl = 0; atl < 2; ++atl)
#pragma unroll
      for (int kk = 0; kk < 2; ++kk) {
        const float* p = base + atl * 1024 + kk * 32;
        buf[(atl * 2 + kk) * 2 + 0] = reinterpret_cast<const float4*>(p)[0];
        buf[(atl * 2 + kk) * 2 + 1] = reinterpret_cast<const float4*>(p)[1];
      }
  };

  // lgkmcnt-only barrier: orders LDS traffic across waves WITHOUT draining
  // vmcnt (prefetch loads / output stores stay in flight).
  auto lgkm_barrier = [&]() {
    __asm__ volatile("s_waitcnt lgkmcnt(0)" ::: "memory");
    __builtin_amdgcn_s_barrier();
    __asm__ volatile("" ::: "memory");
  };

  issue(xb0, mbase + rs);  // gen-0 loads, in flight through the barrier
  lgkm_barrier();          // weights staged

#pragma unroll
  for (int gen = 0; gen < GENS; ++gen) {
    const int m = mbase + 2 * gen + rs;
    float4* cur = (gen & 1) ? xb1 : xb0;
    float4* nxt = (gen & 1) ? xb0 : xb1;

    // ---------------- Stage 1: C1[a-half] = Xm_half * B^T ----------------
#pragma unroll
    for (int atl = 0; atl < 2; ++atl) {
      const int at = A0 + atl;
      float4v acc[4];
#pragma unroll
      for (int qt = 0; qt < 4; ++qt) acc[qt] = vzero;
#pragma unroll
      for (int kk = 0; kk < 2; ++kk) {
        short8v xf = cvt8(cur[(atl * 2 + kk) * 2], cur[(atl * 2 + kk) * 2 + 1]);
#pragma unroll
        for (int qt = 0; qt < 4; ++qt) {
          short8v bfrk = *reinterpret_cast<const short8v*>(
              &bw[(16 * qt + c) * 64 + ((32 * kk + 8 * g) ^ swz)]);
          acc[qt] = __builtin_amdgcn_mfma_f32_16x16x32_bf16(
              xf, bfrk, acc[qt], 0, 0, 0);
        }
      }
      // lane holds C1[16at+4g+b][16qt+c]; store transposed Y1T[q][a], swizzled
#pragma unroll
      for (int qt = 0; qt < 4; ++qt) {
        short4v v;
        v[0] = f2bf(acc[qt][0]); v[1] = f2bf(acc[qt][1]);
        v[2] = f2bf(acc[qt][2]); v[3] = f2bf(acc[qt][3]);
        int idx = ((16 * qt + c) * 64 + 16 * at + 4 * g) ^ swz;
        *reinterpret_cast<short4v*>(&yw[idx]) = v;
      }
    }

    if (gen + 1 < GENS) issue(nxt, m + 2);  // prefetch next gen's half-row

    lgkm_barrier();  // both a-halves of y1 complete

    // ---------------- Stage 2: C2^T[q-half] = Y1^T * A^T ----------------
    short8v yfr[2][2];  // frag(qtl,kk): Y1T[16(2*half+qtl)+c][32kk+8g+i]
#pragma unroll
    for (int qtl = 0; qtl < 2; ++qtl)
#pragma unroll
      for (int kk = 0; kk < 2; ++kk) {
        int idx = ((16 * (2 * half + qtl) + c) * 64) + ((32 * kk + 8 * g) ^ swz);
        yfr[qtl][kk] = *reinterpret_cast<const short8v*>(&yw[idx]);
      }

    lgkm_barrier();  // yfr loaded in ALL waves -> y1[rs] reusable as outbuf

    float* ob = reinterpret_cast<float*>(yw);  // 2048 floats = 32 p x 64 q
    float* om = out + (size_t)m * 4096;

#pragma unroll
    for (int round = 0; round < 2; ++round) {  // p-halves: pt in {2r, 2r+1}
#pragma unroll
      for (int ptl = 0; ptl < 2; ++ptl) {
        const int pt = 2 * round + ptl;
        short8v afr[2];  // frag(kk): A[16pt+c][32kk+8g+i]
#pragma unroll
        for (int kk = 0; kk < 2; ++kk)
          afr[kk] = *reinterpret_cast<const short8v*>(
              &aw[(16 * pt + c) * 64 + ((32 * kk + 8 * g) ^ swz)]);
#pragma unroll
        for (int qtl = 0; qtl < 2; ++qtl) {
          // lane holds C2[p=16pt+c][q=16(2*half+qtl)+4g+b]
          const int n = (16 * pt + c) * 64 + 16 * (2 * half + qtl) + 4 * g;
          float4 bv = *reinterpret_cast<const float4*>(bias + n);
          float4v acc; acc[0] = bv.x; acc[1] = bv.y; acc[2] = bv.z; acc[3] = bv.w;
#pragma unroll
          for (int kk = 0; kk < 2; ++kk)
            acc = __builtin_amdgcn_mfma_f32_16x16x32_bf16(
                yfr[qtl][kk], afr[kk], acc, 0, 0, 0);
          // outbuf: local p row = 16ptl+c, col q ^ row-swizzle
          const int orow = 16 * ptl + c;  // orow&7 == c&7
          const int ocol = (16 * (2 * half + qtl) + 4 * g) ^ swz;
          *reinterpret_cast<float4v*>(&ob[orow * 64 + ocol]) = acc;
        }
      }

      lgkm_barrier();  // outbuf complete for this round

      // Cooperative CONTIGUOUS nt stores: row's 2 waves store 8 KB as
      // 8 x 1KB instructions (4 complete 256B lines each) -> L3 bypass.
#pragma unroll
      for (int i = 0; i < 4; ++i) {
        const int f = (half * 4 + i) * 256 + 4 * lane;  // float idx in round
        const int frow = f >> 6;
        const int fcol = (f & 63) ^ ((frow & 7) << 3);
        float4v v = *reinterpret_cast<const float4v*>(&ob[frow * 64 + fcol]);
        __builtin_nontemporal_store(
            v, reinterpret_cast<float4v*>(om + 2048 * round + f));
      }

      lgkm_barrier();  // outbuf reads done before next round / next gen
    }
  }
}

extern "C" void kernel_launch(void* const* d_in, const int* in_sizes, int n_in,
                              void* d_out, int out_size, void* d_ws, size_t ws_size,
                              hipStream_t stream) {
  (void)in_sizes; (void)n_in; (void)out_size; (void)d_ws; (void)ws_size;
  const float* x    = (const float*)d_in[0];
  const float* A    = (const float*)d_in[1];
  const float* B    = (const float*)d_in[2];
  const float* bias = (const float*)d_in[3];
  float* out = (float*)d_out;

  dim3 grid(8192 / (2 * GENS)), block(256);
  hipLaunchKernelGGL(kron64_kernel, grid, block, 0, stream, x, A, B, bias, out);
}